// Round 2
// baseline (197.706 us; speedup 1.0000x reference)
//
#include <hip/hip_runtime.h>
#include <hip/hip_bf16.h>

#define NB 256
#define IN_F 16
#define HID 64
#define NGP 4
#define PW 68   // xcb row stride (floats); 16B-aligned rows, broadcast reads

// ---------------- compile-time algebra tables ----------------
namespace alg {
constexpr int popc(int x){int c=0;while(x){c+=x&1;x>>=1;}return c;}
struct Tables {
  int qt[64];
  int perm[64];
  int inv[64];
  unsigned char kslot[64][64];// [j_slot][i_slot] -> k_slot
  unsigned char widx [64][64];// [j_slot][i_slot] -> qt_i*16+qt_j*4+qt_k
  unsigned char sgn  [64][64];
};
constexpr Tables build(){
  Tables t{};
  int mask[64]={}; int pos[64]={};
  int idx=0;
  for(int pc=0;pc<=6;++pc) for(int m=0;m<64;++m) if(popc(m)==pc) mask[idx++]=m;
  for(int i=0;i<64;++i) pos[mask[i]]=i;
  for(int i=0;i<64;++i) t.qt[i]=popc(mask[i])&3;
  int s=0;
  for(int c=0;c<4;++c) for(int i=0;i<64;++i) if(t.qt[i]==c){t.perm[s]=i;t.inv[i]=s;++s;}
  for(int js=0;js<64;++js) for(int is=0;is<64;++is){
    int oi=t.perm[is], oj=t.perm[js];
    int mk=mask[oi]^mask[oj];
    int ok=pos[mk];
    t.kslot[js][is]=(unsigned char)t.inv[ok];
    t.widx [js][is]=(unsigned char)(t.qt[oi]*16+t.qt[oj]*4+t.qt[ok]);
    int scnt=0, tt=mask[oi]>>1;
    while(tt){scnt+=popc(tt&mk);tt>>=1;}
    t.sgn[js][is]=(unsigned char)(scnt&1);
  }
  return t;
}
constexpr Tables T = build();
// class-contiguous slot ranges: sizes 16,12,16,20
constexpr int CLS_BEG[4] = {0,16,28,44};
constexpr int CLS_END[4] = {16,28,44,64};
}

// ---------------- prep: transpose weights into workspace ----------------
// lw_t[((l*4+c)*64+m)*64+f] = gp_lin_w[((l*64+f)*64+m)*4+c]   (65536 floats)
// gpw_t[(l*64+k)*64+f]      = gp_w[(l*64+f)*64+k]             (16384 floats)
// w1t [f2*64+f]             = mlp_w1[f*64+f2]                 ( 4096 floats)
__global__ void ga_prep(const float* __restrict__ gp_lin_w,
                        const float* __restrict__ gp_w,
                        const float* __restrict__ mlp_w1,
                        float* __restrict__ lw_t, float* __restrict__ gpw_t,
                        float* __restrict__ w1t,
                        float* __restrict__ out) {
  const int bx = blockIdx.x, t = threadIdx.x;
  if (bx == 0 && t == 0) out[0] = 0.f;   // mean accumulator init
  if (bx < 256) {
    int o = bx*256 + t;
    int f = o & 63, m = (o>>6)&63, c = (o>>12)&3, l = (o>>14)&3;
    lw_t[o] = gp_lin_w[((l*64+f)*64+m)*4 + c];
  } else if (bx < 320) {
    int o = (bx-256)*256 + t;
    int f = o & 63, k = (o>>6)&63, l = (o>>12)&3;
    gpw_t[o] = gp_w[(l*64+f)*64 + k];
  } else {
    int o = (bx-320)*256 + t;          // 16 blocks * 256 = 4096
    int f = o & 63, f2 = o >> 6;
    w1t[o] = mlp_w1[f*64 + f2];
  }
}

// ---------------- GP body: 4 j-slots, fully unrolled vs constexpr tables ----
template<int JQ>
__device__ __forceinline__ void gp_body4(const float* __restrict__ xbcf,
    const float (&y)[64], const float (&w)[16], float (&acc)[4]) {
  #pragma unroll
  for (int is = 0; is < 64; ++is) {
    const float xi = xbcf[is*64];
    #pragma unroll
    for (int jj = 0; jj < 4; ++jj) {
      const int js = JQ*4 + jj;
      const int k  = alg::T.kslot[js][is];
      const int wi = alg::T.widx [js][is];
      const int w16i = ((wi>>4)<<2) | (wi&3);    // qi*4 + qk (qj fixed per JQ)
      const float tp = w[w16i] * y[k];
      acc[jj] = alg::T.sgn[js][is] ? fmaf(-tp, xi, acc[jj])
                                   : fmaf( tp, xi, acc[jj]);
    }
  }
}

// ---------------- main fused kernel: one block (1024 thr) per batch element ----
__global__ __launch_bounds__(1024, 1) void ga_main(
    const float* __restrict__ points, const float* __restrict__ products,
    const float* __restrict__ lin_w,  const float* __restrict__ lin_b,
    const float* __restrict__ gp_a,
    const float* __restrict__ mlp_b1,
    const float* __restrict__ mlp_w2, const float* __restrict__ mlp_b2,
    const float* __restrict__ lw_t,   const float* __restrict__ gpw_t,
    const float* __restrict__ w1t,
    float* __restrict__ d_out)
{
  __shared__ __align__(16) float xcb[64*PW];   // [channel][blade-slot]
  __shared__ float xbc[64*64];                 // [blade-slot][channel]
  __shared__ float ybc[64*64];                 // [blade-slot][channel]
  __shared__ float invn[4*64];                 // [class][channel]
  __shared__ float red[16*64];                 // [jq][channel] partials
  __shared__ float pts[96];
  __shared__ float ynrm[64];

  const int t  = threadIdx.x;
  const int b  = blockIdx.x;
  const int f  = t & 63;
  const int jq = t >> 6;                       // 0..15, wave-uniform
  const int c  = (jq>=4) + (jq>=7) + (jq>=11); // class of this thread's 4 slots

  for (int i = t; i < 64*PW; i += 1024) xcb[i] = 0.f;
  for (int i = t; i < 64*64; i += 1024) xbc[i] = 0.f;
  if (t < 96) pts[t] = points[b*96 + t];
  __syncthreads();

  // phase 0: embed grade-1 + first qt-linear
  if (t < 64) {
    float a[6] = {0,0,0,0,0,0};
    for (int m = 0; m < IN_F; ++m) {
      float lw = lin_w[(t*IN_F+m)*4 + 1];   // qt(grade1)=1
      #pragma unroll
      for (int g = 0; g < 6; ++g) a[g] = fmaf(pts[m*6+g], lw, a[g]);
    }
    float bias = lin_b[t];
    xcb[t*PW + 0] = bias; xbc[0*64 + t] = bias;
    #pragma unroll
    for (int g = 0; g < 6; ++g) {
      xcb[t*PW + 16+g] = a[g];
      xbc[(16+g)*64 + t] = a[g];
    }
  }
  __syncthreads();

  float gacc[4];

  for (int l = 0; l < NGP; ++l) {
    // ---- qt-linear: 4 outputs/thread, single class, broadcast x reads ----
    float lacc[4] = {0.f,0.f,0.f,0.f};
    {
      const float* lw = lw_t + ((l*4+c)*64)*64 + f;
      const float* xr = xcb + jq*4;
      #pragma unroll 8
      for (int m = 0; m < 64; ++m) {
        const float  wv = lw[m*64];
        const float4 x4 = *(const float4*)(xr + m*PW);
        lacc[0] = fmaf(wv, x4.x, lacc[0]);
        lacc[1] = fmaf(wv, x4.y, lacc[1]);
        lacc[2] = fmaf(wv, x4.z, lacc[2]);
        lacc[3] = fmaf(wv, x4.w, lacc[3]);
      }
    }
    #pragma unroll
    for (int ii=0;ii<4;++ii) ybc[(jq*4+ii)*64 + f] = lacc[ii];
    __syncthreads();

    // ---- per-(channel,class) norms -> folded inverse scales (waves 0-3) ----
    if (t < 256) {
      const int cc = t >> 6;
      float s = 0.f;
      for (int i = alg::CLS_BEG[cc]; i < alg::CLS_END[cc]; ++i) {
        float v = ybc[i*64+f]; s = fmaf(v,v,s);
      }
      s = fmaxf(s, 1e-12f);
      float nrm = sqrtf(s);
      float av  = gp_a[(l*64+f)*4 + cc];
      float sig = 1.f/(1.f + expf(-av));
      float nn  = sig*(nrm-1.f) + 1.f;
      invn[cc*64+f] = 1.f/(nn + 1e-6f);
    }
    __syncthreads();

    // ---- geometric product ----
    float yreg[64];
    #pragma unroll
    for (int k=0;k<64;++k) yreg[k] = ybc[k*64+f];
    float w16[16];
    {
      const float in0 = invn[0*64+f], in1 = invn[1*64+f],
                  in2 = invn[2*64+f], in3 = invn[3*64+f];
      const float* wrow = gpw_t + l*4096 + f;   // [widx][f], coalesced
      #pragma unroll
      for (int qi=0;qi<4;++qi) {
        w16[qi*4+0] = wrow[(qi*16 + c*4 + 0)*64] * in0;
        w16[qi*4+1] = wrow[(qi*16 + c*4 + 1)*64] * in1;
        w16[qi*4+2] = wrow[(qi*16 + c*4 + 2)*64] * in2;
        w16[qi*4+3] = wrow[(qi*16 + c*4 + 3)*64] * in3;
      }
    }
    #pragma unroll
    for (int ii=0;ii<4;++ii) gacc[ii]=0.f;
    {
      const float* xbcf = xbc + f;
      switch (jq) {
        case  0: gp_body4< 0>(xbcf, yreg, w16, gacc); break;
        case  1: gp_body4< 1>(xbcf, yreg, w16, gacc); break;
        case  2: gp_body4< 2>(xbcf, yreg, w16, gacc); break;
        case  3: gp_body4< 3>(xbcf, yreg, w16, gacc); break;
        case  4: gp_body4< 4>(xbcf, yreg, w16, gacc); break;
        case  5: gp_body4< 5>(xbcf, yreg, w16, gacc); break;
        case  6: gp_body4< 6>(xbcf, yreg, w16, gacc); break;
        case  7: gp_body4< 7>(xbcf, yreg, w16, gacc); break;
        case  8: gp_body4< 8>(xbcf, yreg, w16, gacc); break;
        case  9: gp_body4< 9>(xbcf, yreg, w16, gacc); break;
        case 10: gp_body4<10>(xbcf, yreg, w16, gacc); break;
        case 11: gp_body4<11>(xbcf, yreg, w16, gacc); break;
        case 12: gp_body4<12>(xbcf, yreg, w16, gacc); break;
        case 13: gp_body4<13>(xbcf, yreg, w16, gacc); break;
        case 14: gp_body4<14>(xbcf, yreg, w16, gacc); break;
        default: gp_body4<15>(xbcf, yreg, w16, gacc); break;
      }
    }
    __syncthreads();           // all xbc reads done before overwrite
    if (l < NGP-1) {
      #pragma unroll
      for (int ii=0;ii<4;++ii) {
        const int s = jq*4+ii;
        xcb[f*PW + s]  = gacc[ii];
        xbc[s*64 + f]  = gacc[ii];
      }
      __syncthreads();
    }
  }

  // ---- tail: blade-norm -> MLP -> loss ----
  float ss = 0.f;
  #pragma unroll
  for (int ii=0;ii<4;++ii) ss = fmaf(gacc[ii],gacc[ii],ss);
  red[jq*64+f] = ss;
  __syncthreads();
  if (t < 64) {
    float s = 0.f;
    #pragma unroll
    for (int q=0;q<16;++q) s += red[q*64+t];
    ynrm[t] = sqrtf(s);
  }
  __syncthreads();
  {
    float hp = 0.f;
    #pragma unroll
    for (int ii=0;ii<4;++ii) {
      const int f2 = jq*4+ii;
      hp = fmaf(w1t[f2*64+f], ynrm[f2], hp);   // coalesced (transposed)
    }
    red[jq*64+f] = hp;
  }
  __syncthreads();
  if (t < 64) {
    float hpre = mlp_b1[t];
    #pragma unroll
    for (int q=0;q<16;++q) hpre += red[q*64+t];
    float h = hpre / (1.f + expf(-hpre));   // silu
    float p = h * mlp_w2[t];
    #pragma unroll
    for (int off = 32; off > 0; off >>= 1) p += __shfl_down(p, off, 64);
    if (t == 0) {
      float pred = p + mlp_b2[0];
      float d = pred - products[b];
      float loss = d*d;
      d_out[1+b] = loss;
      atomicAdd(d_out, loss * (1.f/256.f));
    }
  }
}

extern "C" void kernel_launch(void* const* d_in, const int* in_sizes, int n_in,
                              void* d_out, int out_size, void* d_ws, size_t ws_size,
                              hipStream_t stream) {
  const float* points   = (const float*)d_in[0];
  const float* products = (const float*)d_in[1];
  const float* lin_w    = (const float*)d_in[2];
  const float* lin_b    = (const float*)d_in[3];
  const float* gp_lin_w = (const float*)d_in[4];
  const float* gp_a     = (const float*)d_in[5];
  const float* gp_w     = (const float*)d_in[6];
  const float* mlp_w1   = (const float*)d_in[7];
  const float* mlp_b1   = (const float*)d_in[8];
  const float* mlp_w2   = (const float*)d_in[9];
  const float* mlp_b2   = (const float*)d_in[10];
  float* out = (float*)d_out;

  float* lw_t  = (float*)d_ws;        // 65536 floats
  float* gpw_t = lw_t + 65536;        // 16384 floats
  float* w1t   = gpw_t + 16384;       //  4096 floats

  ga_prep<<<336, 256, 0, stream>>>(gp_lin_w, gp_w, mlp_w1, lw_t, gpw_t, w1t, out);
  ga_main<<<NB, 1024, 0, stream>>>(points, products, lin_w, lin_b, gp_a,
                                   mlp_b1, mlp_w2, mlp_b2,
                                   lw_t, gpw_t, w1t, out);
}